// Round 9
// baseline (80.958 us; speedup 1.0000x reference)
//
#include <hip/hip_runtime.h>

// Soft decision tree DEPTH=8, 255 internal nodes (heap order), 256 leaves,
// 10 classes, B=131072, 32 feats. fp32 in/out.
//
// R12 = R11 with the eval phase restructured into three EXPLICIT phases so
// no LDS read sits inside the probability dependence tree:
//   A: all 12 node-record loads (s_nd shifted +1 -> d5/d6/d7 sibling pairs
//      16B-aligned -> 7x ds_read_b128 + 5x ds_read_b64, all independent).
//   B: all 19 x-gather ds_read_b64 (addresses depend only on records).
//      sched_barrier(0) pins loads above / tree below.
//   C: probability tree = pure ALU (fma/rcp/mul), ~8x30cy critical path.
// Rationale: R8 (occupancy), R9 (issue counts), R10 (chain depth x waves),
// R11 (generations) each moved ~1us off ~25us; issue arithmetic says ~5us;
// the invariant residual must be LDS-latency exposure INSIDE the tree,
// which none of those levers touched. This forces the m97-style decoupled
// schedule at source level.
// Unchanged from R11 (verified): RPB=32, grid 4096, 2 barriers, 16
// sections, sig2 ILP=2, P [32][512B] swizzle ((r^(r>>3))&7)<<4, MFMA
// A k-group (lane>>4)*8 <-> B k-label, C/D col=lane&15 row=(lane>>4)*4+reg,
// waves 0/1 do the 2 row-tiles x K=256. LDS 23.8KB -> 4 blocks/CU.
// Falsification: dur_us >= 78 -> all in-kernel theories exhausted; declare
// practical floor (fill 43us @ its own HBM roofline + ~17us harness fixed).

#define NFEAT 32
#define NCLS  10
#define TPB   256
#define RPB   32           // rows per block -> grid 4096
#define XPITCH 34          // padded f32 pitch, EVEN: row-pair b64 aligned
#define L2E   1.4426950408889634f

typedef _Float16 f16x8 __attribute__((ext_vector_type(8)));
typedef float    f32x4 __attribute__((ext_vector_type(4)));

__device__ __forceinline__ float fexp2(float z) {
#if __has_builtin(__builtin_amdgcn_exp2f)
  return __builtin_amdgcn_exp2f(z);
#else
  return exp2f(z);
#endif
}
__device__ __forceinline__ float frcp(float z) {
#if __has_builtin(__builtin_amdgcn_rcpf)
  return __builtin_amdgcn_rcpf(z);
#else
  return 1.0f / z;
#endif
}

// Pure-ALU paired sigmoid: a = 1/(1 + tpow*w); pr = p*a; pl = p - pr.
__device__ __forceinline__ void sigp(float tp, float2 w, float p0, float p1,
                                     float& l0, float& r0, float& l1, float& r1) {
  const float a0 = frcp(__builtin_fmaf(tp, w.x, 1.0f));
  const float a1 = frcp(__builtin_fmaf(tp, w.y, 1.0f));
  r0 = p0 * a0;  l0 = p0 - r0;
  r1 = p1 * a1;  l1 = p1 - r1;
}
// pack two rows' (l,r) as half2 words (low = LEFT leaf)
__device__ __forceinline__ void packlp(float l0, float r0, float l1, float r1,
                                       unsigned& u0, unsigned& u1) {
  const _Float16 hl0 = (_Float16)l0, hr0 = (_Float16)r0;
  const _Float16 hl1 = (_Float16)l1, hr1 = (_Float16)r1;
  u0 = ((unsigned)__builtin_bit_cast(unsigned short, hr0) << 16) |
        (unsigned)__builtin_bit_cast(unsigned short, hl0);
  u1 = ((unsigned)__builtin_bit_cast(unsigned short, hr1) << 16) |
        (unsigned)__builtin_bit_cast(unsigned short, hl1);
}

__global__ __launch_bounds__(TPB, 4)
void dt_kernel(const float* __restrict__ x,
               const float* __restrict__ thr,
               const int*   __restrict__ feats,
               const int*   __restrict__ leafc,
               float*       __restrict__ out) {
  __shared__ __align__(16) int2  s_nd[256];             // node n at [n+1] (2KB)
  __shared__ __align__(16) float s_xT[NFEAT * XPITCH];  // w = 2^-x2 (4352B)
  __shared__ __align__(16) char  s_P[RPB * 512];        // P f16 (16KB)
  __shared__ int s_lc[256];                             // leaf classes (1KB)

  const int t    = threadIdx.x;
  const int lane = t & 63;
  const int rp   = t & 15;                  // row-pair index 0..15
  const int sec  = t >> 4;                  // sixteenth-subtree 0..15
  const int w    = t >> 6;                  // wave id 0..3

  // --- stage nodes (tpow = 2^(thr*log2e)) at s_nd[n+1], leafc, x ---
  if (t < 255) {
    s_nd[t + 1] = make_int2(__float_as_int(fexp2(thr[t] * L2E)), feats[t]);
  }
  s_lc[t] = leafc[t];
  {
    const float4* xg = (const float4*)x + (size_t)blockIdx.x * (RPB * NFEAT / 4);
    const float4 v = xg[t];                 // one float4 per thread
    const int r  = t >> 3;                  // local row 0..31
    const int c0 = (t & 7) * 4;             // first feature column
    s_xT[(c0 + 0) * XPITCH + r] = fexp2(-v.x * L2E);
    s_xT[(c0 + 1) * XPITCH + r] = fexp2(-v.y * L2E);
    s_xT[(c0 + 2) * XPITCH + r] = fexp2(-v.z * L2E);
    s_xT[(c0 + 3) * XPITCH + r] = fexp2(-v.w * L2E);
  }

  __syncthreads();                          // barrier 1 of 2

  // ===== Phase A: ALL node-record loads (independent, deep-queued) =====
  const int n4 = 15 + sec;                  // depth-4 subtree root
  const int2 ndP0 = s_nd[1];                              // node 0
  const int2 ndP1 = s_nd[2 + (sec >> 3)];                 // node 1+(sec>>3)
  const int2 ndP2 = s_nd[4 + (sec >> 2)];                 // node 3+(sec>>2)
  const int2 ndP3 = s_nd[8 + (sec >> 1)];                 // node 7+(sec>>1)
  const int2 nd4  = s_nd[16 + sec];                       // node n4
  const int4 d5   = *(const int4*)&s_nd[32 + 2 * sec];    // nodes 2n4+1,2n4+2
  const int4 d6a  = *(const int4*)&s_nd[64 + 4 * sec];    // nodes 4n4+3,4n4+4
  const int4 d6b  = *(const int4*)&s_nd[66 + 4 * sec];    // nodes 4n4+5,4n4+6
  const int4 d7a  = *(const int4*)&s_nd[128 + 8 * sec];   // nodes 8n4+7,8n4+8
  const int4 d7b  = *(const int4*)&s_nd[130 + 8 * sec];   // 8n4+9,10
  const int4 d7c  = *(const int4*)&s_nd[132 + 8 * sec];   // 8n4+11,12
  const int4 d7d  = *(const int4*)&s_nd[134 + 8 * sec];   // 8n4+13,14

  // ===== Phase B: ALL x-gathers (addresses depend only on records) =====
#define WV(fidx) (*(const float2*)&s_xT[(fidx) * XPITCH + 2 * rp])
  const float2 wP0 = WV(ndP0.y), wP1 = WV(ndP1.y);
  const float2 wP2 = WV(ndP2.y), wP3 = WV(ndP3.y);
  const float2 w4  = WV(nd4.y);
  const float2 w5a = WV(d5.y),  w5b = WV(d5.w);
  const float2 w6a = WV(d6a.y), w6b = WV(d6a.w);
  const float2 w6c = WV(d6b.y), w6d = WV(d6b.w);
  const float2 w7a = WV(d7a.y), w7b = WV(d7a.w);
  const float2 w7c = WV(d7b.y), w7d = WV(d7b.w);
  const float2 w7e = WV(d7c.y), w7f = WV(d7c.w);
  const float2 w7g = WV(d7d.y), w7h = WV(d7d.w);
#undef WV
  __builtin_amdgcn_sched_barrier(0);        // loads above, tree below

  // ===== Phase C: pure-ALU probability tree =====
  float l0, r0, l1, r1;
  sigp(__int_as_float(ndP0.x), wP0, 1.0f, 1.0f, l0, r0, l1, r1);
  float p0 = (sec & 8) ? r0 : l0, p1 = (sec & 8) ? r1 : l1;
  sigp(__int_as_float(ndP1.x), wP1, p0, p1, l0, r0, l1, r1);
  p0 = (sec & 4) ? r0 : l0;  p1 = (sec & 4) ? r1 : l1;
  sigp(__int_as_float(ndP2.x), wP2, p0, p1, l0, r0, l1, r1);
  p0 = (sec & 2) ? r0 : l0;  p1 = (sec & 2) ? r1 : l1;
  sigp(__int_as_float(ndP3.x), wP3, p0, p1, l0, r0, l1, r1);
  p0 = (sec & 1) ? r0 : l0;  p1 = (sec & 1) ? r1 : l1;

  float a_l0, a_r0, a_l1, a_r1;
  sigp(__int_as_float(nd4.x), w4, p0, p1, a_l0, a_r0, a_l1, a_r1);
  float b0_l0, b0_r0, b0_l1, b0_r1, b1_l0, b1_r0, b1_l1, b1_r1;
  sigp(__int_as_float(d5.x), w5a, a_l0, a_l1, b0_l0, b0_r0, b0_l1, b0_r1);
  sigp(__int_as_float(d5.z), w5b, a_r0, a_r1, b1_l0, b1_r0, b1_l1, b1_r1);
  float c0_l0, c0_r0, c0_l1, c0_r1, c1_l0, c1_r0, c1_l1, c1_r1;
  float c2_l0, c2_r0, c2_l1, c2_r1, c3_l0, c3_r0, c3_l1, c3_r1;
  sigp(__int_as_float(d6a.x), w6a, b0_l0, b0_l1, c0_l0, c0_r0, c0_l1, c0_r1);
  sigp(__int_as_float(d6a.z), w6b, b0_r0, b0_r1, c1_l0, c1_r0, c1_l1, c1_r1);
  sigp(__int_as_float(d6b.x), w6c, b1_l0, b1_l1, c2_l0, c2_r0, c2_l1, c2_r1);
  sigp(__int_as_float(d6b.z), w6d, b1_r0, b1_r1, c3_l0, c3_r0, c3_l1, c3_r1);

  uint4 ua0, ua1, ub0, ub1;
  sigp(__int_as_float(d7a.x), w7a, c0_l0, c0_l1, l0, r0, l1, r1);
  packlp(l0, r0, l1, r1, ua0.x, ua1.x);
  sigp(__int_as_float(d7a.z), w7b, c0_r0, c0_r1, l0, r0, l1, r1);
  packlp(l0, r0, l1, r1, ua0.y, ua1.y);
  sigp(__int_as_float(d7b.x), w7c, c1_l0, c1_l1, l0, r0, l1, r1);
  packlp(l0, r0, l1, r1, ua0.z, ua1.z);
  sigp(__int_as_float(d7b.z), w7d, c1_r0, c1_r1, l0, r0, l1, r1);
  packlp(l0, r0, l1, r1, ua0.w, ua1.w);
  sigp(__int_as_float(d7c.x), w7e, c2_l0, c2_l1, l0, r0, l1, r1);
  packlp(l0, r0, l1, r1, ub0.x, ub1.x);
  sigp(__int_as_float(d7c.z), w7f, c2_r0, c2_r1, l0, r0, l1, r1);
  packlp(l0, r0, l1, r1, ub0.y, ub1.y);
  sigp(__int_as_float(d7d.x), w7g, c3_l0, c3_l1, l0, r0, l1, r1);
  packlp(l0, r0, l1, r1, ub0.z, ub1.z);
  sigp(__int_as_float(d7d.z), w7h, c3_r0, c3_r1, l0, r0, l1, r1);
  packlp(l0, r0, l1, r1, ub0.w, ub1.w);

  // --- write 32B leaf span per row, swizzled (flips addr bits 4-6 only) ---
  {
    const int row0 = 2 * rp, row1 = row0 + 1;
    const int swz0 = ((row0 ^ (row0 >> 3)) & 7) << 4;
    const int swz1 = ((row1 ^ (row1 >> 3)) & 7) << 4;
    char* q0 = s_P + row0 * 512;
    char* q1 = s_P + row1 * 512;
    const int qb = 32 * sec;
    *(uint4*)(q0 + ((qb)      ^ swz0)) = ua0;
    *(uint4*)(q0 + ((qb + 16) ^ swz0)) = ub0;
    *(uint4*)(q1 + ((qb)      ^ swz1)) = ua1;
    *(uint4*)(q1 + ((qb + 16) ^ swz1)) = ub1;
  }

  __syncthreads();                          // barrier 2 of 2

  // --- waves 0,1: tile w (rows 16w..16w+16) x K=256; waves 2,3 retire ---
  if (w < 2) {
    const int col16 = lane & 15;
    const int kb    = (lane >> 4) * 8;      // k-group elem base
    const int arow  = 16 * w + col16;
    const int aswz  = ((arow ^ (arow >> 3)) & 7) << 4;
    const char* ap  = s_P + arow * 512;
    f32x4 acc = {0.f, 0.f, 0.f, 0.f};
#pragma unroll
    for (int c = 0; c < 8; ++c) {
      // B onehot fragment for leaves [32c, 32c+32)
      const int4 cA = *(const int4*)&s_lc[c * 32 + kb];
      const int4 cB = *(const int4*)&s_lc[c * 32 + kb + 4];
      uint4 u;
      u.x = ((cA.x == col16) ? 0x3C00u : 0u) | (((cA.y == col16) ? 0x3C00u : 0u) << 16);
      u.y = ((cA.z == col16) ? 0x3C00u : 0u) | (((cA.w == col16) ? 0x3C00u : 0u) << 16);
      u.z = ((cB.x == col16) ? 0x3C00u : 0u) | (((cB.y == col16) ? 0x3C00u : 0u) << 16);
      u.w = ((cB.z == col16) ? 0x3C00u : 0u) | (((cB.w == col16) ? 0x3C00u : 0u) << 16);
      const f16x8 Bf = __builtin_bit_cast(f16x8, u);
      const f16x8 a  = *(const f16x8*)(ap + ((64 * c + 2 * kb) ^ aswz));
      acc = __builtin_amdgcn_mfma_f32_16x16x32_f16(a, Bf, acc, 0, 0, 0);
    }
    // D layout col=lane&15, row=(lane>>4)*4+reg (verified)
    if (col16 < NCLS) {
      const size_t gr = (size_t)blockIdx.x * RPB + 16 * w + (lane >> 4) * 4;
#pragma unroll
      for (int j = 0; j < 4; ++j) {
        out[(gr + j) * NCLS + col16] = acc[j];
      }
    }
  }
}

extern "C" void kernel_launch(void* const* d_in, const int* in_sizes, int n_in,
                              void* d_out, int out_size, void* d_ws, size_t ws_size,
                              hipStream_t stream) {
  const float* x     = (const float*)d_in[0];
  const float* thr   = (const float*)d_in[1];
  const int*   feats = (const int*)d_in[2];
  const int*   leafc = (const int*)d_in[3];
  float*       out   = (float*)d_out;

  const int B    = in_sizes[0] / NFEAT;        // 131072
  const int grid = B / RPB;                    // 4096
  dt_kernel<<<grid, TPB, 0, stream>>>(x, thr, feats, leafc, out);
}